// Round 1
// 534.279 us; speedup vs baseline: 1.0588x; 1.0588x over previous
//
#include <hip/hip_runtime.h>
#include <hip/hip_bf16.h>

typedef __hip_bfloat16 bf16;
typedef __attribute__((ext_vector_type(8))) short bf16x8;
typedef __attribute__((ext_vector_type(4))) short s16x4;
typedef __attribute__((ext_vector_type(4))) float f32x4;

__device__ __forceinline__ float b2f(bf16 v) { return __bfloat162float(v); }
__device__ __forceinline__ bf16  f2b(float v) { return __float2bfloat16(v); }
__device__ __forceinline__ float ldf(const bf16* p)  { return __bfloat162float(*p); }
__device__ __forceinline__ float ldf(const float* p) { return *p; }
__device__ __forceinline__ void  stf(bf16* p, float v)  { *p = __float2bfloat16(v); }
__device__ __forceinline__ void  stf(float* p, float v) { *p = v; }

// async global->LDS, 16 B per lane; LDS dest = wave-uniform base + lane*16
__device__ __forceinline__ void load_lds16(const bf16* g, short* lds) {
    __builtin_amdgcn_global_load_lds(
        (const __attribute__((address_space(1))) unsigned int*)g,
        (__attribute__((address_space(3))) unsigned int*)lds, 16, 0, 0);
}

// ---------------------------------------------------------------------------
// LayerNorm over last dim C=1024. One block (256 threads) per row. bf16 out.
// ---------------------------------------------------------------------------
template<typename InT>
__global__ __launch_bounds__(256) void ln_kernel(const InT* __restrict__ x,
                                                 const float* __restrict__ g,
                                                 const float* __restrict__ b,
                                                 bf16* __restrict__ out)
{
    const int C = 1024;
    int row = blockIdx.x;
    int tid = threadIdx.x;
    const InT* xr = x + (size_t)row * C;

    float v[4];
    float s = 0.f, s2 = 0.f;
#pragma unroll
    for (int i = 0; i < 4; ++i) {
        float f = ldf(xr + tid + i * 256);
        v[i] = f; s += f; s2 += f * f;
    }
#pragma unroll
    for (int off = 32; off > 0; off >>= 1) {
        s  += __shfl_down(s,  off, 64);
        s2 += __shfl_down(s2, off, 64);
    }
    __shared__ float red[8];
    int wave = tid >> 6;
    if ((tid & 63) == 0) { red[wave] = s; red[wave + 4] = s2; }
    __syncthreads();
    float ts  = red[0] + red[1] + red[2] + red[3];
    float ts2 = red[4] + red[5] + red[6] + red[7];
    float mu  = ts * (1.f / 1024.f);
    float var = ts2 * (1.f / 1024.f) - mu * mu;
    float rstd = rsqrtf(var + 1e-5f);
#pragma unroll
    for (int i = 0; i < 4; ++i) {
        int c = tid + i * 256;
        out[(size_t)row * C + c] = f2b((v[i] - mu) * rstd * g[c] + b[c]);
    }
}

// ---------------------------------------------------------------------------
// All six weight transposes (fp32 -> bf16, out[n][k] = in[k][n]) in ONE
// kernel. Flat tile id selects matrix + 32x32 tile.
// ---------------------------------------------------------------------------
__global__ __launch_bounds__(256) void prep_weights(
    const float* __restrict__ Wq, const float* __restrict__ Wk,
    const float* __restrict__ Wv, const float* __restrict__ Wo,
    const float* __restrict__ W1, const float* __restrict__ W2,
    bf16* __restrict__ wqkvt, bf16* __restrict__ wot,
    bf16* __restrict__ w1t, bf16* __restrict__ w2t)
{
    __shared__ float t[32][33];
    int tx = threadIdx.x & 31, ty = threadIdx.x >> 5;
    int id = blockIdx.x;
    const float* in; bf16* out; int in_ld, out_ld, n0, k0;
    if (id < 3072) {
        const float* Ws[3] = {Wq, Wk, Wv};
        int m = id >> 10, r = id & 1023;
        int z = r >> 6, rt = r & 63;
        in = Ws[m] + z * 65536;                       // [1024][64]
        out = wqkvt + (size_t)(m * 1024 + z * 64) * 1024;
        in_ld = 64; out_ld = 1024;
        n0 = (rt & 1) * 32; k0 = (rt >> 1) * 32;
    } else if (id < 4096) {
        int r = id - 3072;
        in = Wo; out = wot; in_ld = 1024; out_ld = 1024;
        n0 = (r & 31) * 32; k0 = (r >> 5) * 32;
    } else if (id < 8192) {
        int r = id - 4096;
        in = W1; out = w1t; in_ld = 4096; out_ld = 1024;
        n0 = (r & 127) * 32; k0 = (r >> 7) * 32;
    } else {
        int r = id - 8192;
        in = W2; out = w2t; in_ld = 1024; out_ld = 4096;
        n0 = (r & 31) * 32; k0 = (r >> 5) * 32;
    }
#pragma unroll
    for (int i = 0; i < 4; ++i)
        t[ty + i * 8][tx] = in[(size_t)(k0 + ty + i * 8) * in_ld + n0 + tx];
    __syncthreads();
#pragma unroll
    for (int i = 0; i < 4; ++i)
        out[(size_t)(n0 + ty + i * 8) * out_ld + k0 + tx] = f2b(t[tx][ty + i * 8]);
}

// ---------------------------------------------------------------------------
// V^T: vt[(b*16+h)*64 + d][t] = qkv[(b*T+t)*3072 + 2048 + h*64 + d]
// ---------------------------------------------------------------------------
__global__ __launch_bounds__(256) void vt_kernel(
    const bf16* __restrict__ qkv, bf16* __restrict__ vt, int T)
{
    __shared__ float t[32][33];
    int tx = threadIdx.x & 31, ty = threadIdx.x >> 5;
    int z = blockIdx.z, b = z >> 4, h = z & 15;
    const bf16* in = qkv + (size_t)b * T * 3072 + 2048 + h * 64;  // [t][d] ld 3072
    bf16* out = vt + (size_t)z * 64 * T;                          // [d][t] ld T
    int n0 = blockIdx.x * 32, k0 = blockIdx.y * 32;
#pragma unroll
    for (int i = 0; i < 4; ++i)
        t[ty + i * 8][tx] = b2f(in[(size_t)(k0 + ty + i * 8) * 3072 + n0 + tx]);
    __syncthreads();
#pragma unroll
    for (int i = 0; i < 4; ++i)
        out[(size_t)(n0 + ty + i * 8) * T + k0 + tx] = f2b(t[tx][ty + i * 8]);
}

// ---------------------------------------------------------------------------
// MFMA GEMM: C[M,N] = A[M,K] @ B[K,N], B given TRANSPOSED (Bt[n][k]).
// 128x128 tile, BK=32, 256 thr = 4 waves. XOR-swizzled LDS fragments.
// T3-minimum 2-phase: double-buffered LDS, stage(t+1) issued BEFORE the
// compute of tile t, ONE __syncthreads per K-step (its implicit vmcnt(0)
// drain is exactly the wait the prefetch needs). Staging latency hides
// under the 16-MFMA compute phase; barrier count halved vs the old
// stage->sync->compute->sync loop.
// XCD-aware block remap: flat id -> (by = f % nby, bx = f / nby).
// ---------------------------------------------------------------------------
template<bool RELU, bool HAS_BIAS, bool HAS_RES, typename ResT, typename OutT>
__global__ __launch_bounds__(256) void gemm_bt(
    const bf16* __restrict__ A, int lda,
    const bf16* __restrict__ Bt, int ldb,
    const float* __restrict__ bias,
    const ResT* __restrict__ res, int ldr,
    OutT* __restrict__ Cm, int ldc,
    int M, int N, int K)
{
    __shared__ short As[2][128 * 32];
    __shared__ short Bs[2][128 * 32];
    int tid = threadIdx.x, wv = tid >> 6, ln = tid & 63;

    // XCD-locality remap (see header comment)
    int f = blockIdx.x + blockIdx.y * gridDim.x;
    int nby = gridDim.y;
    int by = f % nby, bx = f / nby;
    int bm0 = by * 128, bn0 = bx * 128;

    int wm = (wv & 1) * 64, wn = (wv >> 1) * 64;
    int quad = ln >> 4, lane15 = ln & 15;

    f32x4 acc[4][4] = {};

    int srow = ln >> 2;                              // row within 16-row chunk
    int scol = (((ln & 3) ^ (srow & 3)) * 8);        // swizzled source col
    int sw   = (quad ^ (lane15 & 3)) * 8;            // swizzled read slot
    const bf16* Ab = A + (size_t)bm0 * lda;
    const bf16* Bb = Bt + (size_t)bn0 * ldb;

    // prologue: stage tile 0 into buffer 0
#pragma unroll
    for (int i = 0; i < 2; ++i) {
        int ch = wv + i * 4;
        load_lds16(Ab + (size_t)(ch * 16 + srow) * lda + scol, &As[0][ch * 16 * 32]);
        load_lds16(Bb + (size_t)(ch * 16 + srow) * ldb + scol, &Bs[0][ch * 16 * 32]);
    }
    __syncthreads();   // drains vmcnt -> tile 0 resident

    int cur = 0;
    for (int k0 = 0; k0 < K; k0 += 32) {
        // issue prefetch of tile t+1 into the other buffer (async, vmcnt)
        if (k0 + 32 < K) {
            int nb = cur ^ 1;
#pragma unroll
            for (int i = 0; i < 2; ++i) {
                int ch = wv + i * 4;
                load_lds16(Ab + (size_t)(ch * 16 + srow) * lda + k0 + 32 + scol,
                           &As[nb][ch * 16 * 32]);
                load_lds16(Bb + (size_t)(ch * 16 + srow) * ldb + k0 + 32 + scol,
                           &Bs[nb][ch * 16 * 32]);
            }
        }
        bf16x8 af[4], bfr[4];
#pragma unroll
        for (int mi = 0; mi < 4; ++mi)
            af[mi] = *(const bf16x8*)&As[cur][(wm + mi * 16 + lane15) * 32 + sw];
#pragma unroll
        for (int ni = 0; ni < 4; ++ni)
            bfr[ni] = *(const bf16x8*)&Bs[cur][(wn + ni * 16 + lane15) * 32 + sw];
#pragma unroll
        for (int mi = 0; mi < 4; ++mi)
#pragma unroll
            for (int ni = 0; ni < 4; ++ni)
                acc[mi][ni] = __builtin_amdgcn_mfma_f32_16x16x32_bf16(
                    af[mi], bfr[ni], acc[mi][ni], 0, 0, 0);
        __syncthreads();   // drains vmcnt: tile t+1 resident; reads of cur done
        cur ^= 1;
    }

#pragma unroll
    for (int mi = 0; mi < 4; ++mi) {
#pragma unroll
        for (int r = 0; r < 4; ++r) {
            int gm = bm0 + wm + mi * 16 + quad * 4 + r;
#pragma unroll
            for (int ni = 0; ni < 4; ++ni) {
                int gn = bn0 + wn + ni * 16 + lane15;
                float v = acc[mi][ni][r];
                if (HAS_BIAS) v += bias[gn];
                if (HAS_RES)  v += ldf(res + (size_t)gm * ldr + gn);
                if (RELU)     v = fmaxf(v, 0.f);
                stf(Cm + (size_t)gm * ldc + gn, v);
            }
        }
    }
}

// ---------------------------------------------------------------------------
// MFMA causal flash attention, S^T form, 128-row q-tile, 512 thr = 8 waves.
// Q held in registers (wave-private). K/V double-buffered in LDS with
// XOR-swizzled layout; prefetch of tile kt+1 issued right after the barrier
// publishing tile kt.
// Changes this round:
//  - qt = gridDim.x-1-blockIdx.x : longest (most k-tiles) blocks dispatch
//    first, short blocks backfill the causal tail -> higher occupancy.
//  - T5 s_setprio(1) around the QK^T and PV MFMA clusters.
//  - T13 defer-max: skip the alpha-rescale of oacc/lrun when
//    __all(pmax <= mrun + 8) -- P bounded by e^8, safe in bf16.
// ---------------------------------------------------------------------------
__global__ __launch_bounds__(512) void attn_kernel(
    const bf16* __restrict__ qkv, const bf16* __restrict__ vt,
    bf16* __restrict__ o, int T)
{
    const int LDQ = 3072;
    const int PS = 72;   // Ps row stride (shorts): 144 B, 16B-aligned
    int qt = (int)gridDim.x - 1 - (int)blockIdx.x;   // longest-first
    int h = blockIdx.y, b = blockIdx.z;
    int tid = threadIdx.x, wv = tid >> 6, ln = tid & 63;
    int quad = ln >> 4, lane15 = ln & 15, r7 = lane15 & 7;

    __shared__ short KV[2][2][64 * 64];   // [buf][0=K [key][d], 1=V [d][key]]
    __shared__ short Ps[8][16 * PS];      // per-wave [qrow16][key64]

    int lr = ln >> 3;                     // 0..7: row within 8-row chunk
    int lc = ((ln & 7) ^ lr) * 8;         // swizzled source col offset

    const bf16* kbase = qkv + (size_t)(b * T) * LDQ + 1024 + h * 64;
    const bf16* vbase = vt + (size_t)((b * 16 + h) * 64) * T;

    // ---- stage Q (128 rows x 64) into KV area, read into regs, then free it
    short* Qarea = &KV[0][0][0];
#pragma unroll
    for (int i = 0; i < 2; ++i) {
        int ch = wv * 2 + i;
        load_lds16(qkv + (size_t)(b * T + qt * 128 + ch * 8 + lr) * LDQ + h * 64 + lc,
                   &Qarea[ch * 512]);
    }
    __syncthreads();   // Q staged (vmcnt drained by barrier)
    bf16x8 qf[2];
#pragma unroll
    for (int ks = 0; ks < 2; ++ks)
        qf[ks] = *(const bf16x8*)&Qarea[(wv * 16 + lane15) * 64 + (((ks * 4 + quad) ^ r7) * 8)];
    __syncthreads();   // all Q reads done before K/V overwrite

    f32x4 oacc[4] = {};
    float mrun = -1e30f, lrun = 0.f;
    const float scale = 0.125f;  // 1/sqrt(64)
    int qmin = qt * 128 + wv * 16;
    int ntiles = 2 * qt + 2;

    // prefetch tile 0 into buf 0 (wave wv stages rows wv*8..wv*8+7)
    load_lds16(kbase + (size_t)(0 * 64 + wv * 8 + lr) * LDQ + lc, &KV[0][0][wv * 8 * 64]);
    load_lds16(vbase + (size_t)(wv * 8 + lr) * T + 0 * 64 + lc, &KV[0][1][wv * 8 * 64]);

    for (int kt = 0; kt < ntiles; ++kt) {
        __syncthreads();   // tile kt published (barrier drains vmcnt)
        if (kt + 1 < ntiles) {
            int nb = (kt + 1) & 1;
            load_lds16(kbase + (size_t)((kt + 1) * 64 + wv * 8 + lr) * LDQ + lc,
                       &KV[nb][0][wv * 8 * 64]);
            load_lds16(vbase + (size_t)(wv * 8 + lr) * T + (kt + 1) * 64 + lc,
                       &KV[nb][1][wv * 8 * 64]);
        }
        if (kt * 64 > qmin + 15) continue;   // fully masked for this wave

        const short* Ks = &KV[kt & 1][0][0];
        const short* Vs = &KV[kt & 1][1][0];

        // S^T = K Q^T : sacc[mi] holds S^T[key = mi*16+quad*4+r][q = lane15]
        f32x4 sacc[4] = {};
        __builtin_amdgcn_s_setprio(1);
#pragma unroll
        for (int ks = 0; ks < 2; ++ks) {
            int so = ((ks * 4 + quad) ^ r7) * 8;
#pragma unroll
            for (int mi = 0; mi < 4; ++mi) {
                bf16x8 kf = *(const bf16x8*)&Ks[(mi * 16 + lane15) * 64 + so];
                sacc[mi] = __builtin_amdgcn_mfma_f32_16x16x32_bf16(kf, qf[ks], sacc[mi], 0, 0, 0);
            }
        }
        __builtin_amdgcn_s_setprio(0);

        // causal mask: only tiles containing this wave's diagonal
        if (kt * 64 + 63 > qmin) {
            int ql = qmin + lane15;
#pragma unroll
            for (int mi = 0; mi < 4; ++mi)
#pragma unroll
                for (int r = 0; r < 4; ++r)
                    if (kt * 64 + mi * 16 + quad * 4 + r > ql) sacc[mi][r] = -3e38f;
        }

        // in-lane row max (16 keys/lane), cross-quad reduce
        float mx = sacc[0][0];
#pragma unroll
        for (int mi = 0; mi < 4; ++mi)
#pragma unroll
            for (int r = 0; r < 4; ++r) mx = fmaxf(mx, sacc[mi][r]);
        mx = fmaxf(mx, __shfl_xor(mx, 16, 64));
        mx = fmaxf(mx, __shfl_xor(mx, 32, 64));
        float pmax = mx * scale;

        // T13 defer-max: only rescale when the running max moved by > 8
        if (!__all(pmax <= mrun + 8.f)) {
            float mn = fmaxf(mrun, pmax);
            float alpha = __expf(mrun - mn);
            mrun = mn;
            lrun *= alpha;
#pragma unroll
            for (int di = 0; di < 4; ++di)
#pragma unroll
                for (int r = 0; r < 4; ++r) oacc[di][r] *= alpha;
        }

        float psum = 0.f;
#pragma unroll
        for (int mi = 0; mi < 4; ++mi) {
            float p[4];
#pragma unroll
            for (int r = 0; r < 4; ++r) {
                p[r] = __expf(fmaf(sacc[mi][r], scale, -mrun));
                psum += p[r];
            }
            short tmp[4];
#pragma unroll
            for (int r = 0; r < 4; ++r) {
                bf16 pb = f2b(p[r]);
                tmp[r] = *(short*)&pb;
            }
            *(s16x4*)&Ps[wv][lane15 * PS + mi * 16 + quad * 4] = *(s16x4*)tmp;
        }
        lrun += psum;

        // O^T += V^T P^T  (wave-private Ps: no barrier needed)
        __builtin_amdgcn_s_setprio(1);
#pragma unroll
        for (int ks = 0; ks < 2; ++ks) {
            int so = ((ks * 4 + quad) ^ r7) * 8;
            bf16x8 pf = *(const bf16x8*)&Ps[wv][lane15 * PS + ks * 32 + quad * 8];
#pragma unroll
            for (int di = 0; di < 4; ++di) {
                bf16x8 vf = *(const bf16x8*)&Vs[(di * 16 + lane15) * 64 + so];
                oacc[di] = __builtin_amdgcn_mfma_f32_16x16x32_bf16(vf, pf, oacc[di], 0, 0, 0);
            }
        }
        __builtin_amdgcn_s_setprio(0);
    }

    // full row l: sum partials across the 4 quads
    lrun += __shfl_xor(lrun, 16, 64);
    lrun += __shfl_xor(lrun, 32, 64);
    float inv = 1.f / lrun;

    size_t row = (size_t)(b * T + qt * 128 + wv * 16 + lane15);
#pragma unroll
    for (int di = 0; di < 4; ++di) {
        short tmp[4];
#pragma unroll
        for (int r = 0; r < 4; ++r) {
            bf16 ob = f2b(oacc[di][r] * inv);
            tmp[r] = *(short*)&ob;
        }
        *(s16x4*)&o[row * 1024 + h * 64 + di * 16 + quad * 4] = *(s16x4*)tmp;
    }
}

// ---------------------------------------------------------------------------
extern "C" void kernel_launch(void* const* d_in, const int* in_sizes, int n_in,
                              void* d_out, int out_size, void* d_ws, size_t ws_size,
                              hipStream_t stream)
{
    (void)in_sizes; (void)n_in; (void)out_size; (void)ws_size;
    const float* x   = (const float*)d_in[0];
    const float* Wq  = (const float*)d_in[1];
    const float* Wk  = (const float*)d_in[2];
    const float* Wv  = (const float*)d_in[3];
    const float* Wo  = (const float*)d_in[4];
    const float* bo  = (const float*)d_in[5];
    const float* g1  = (const float*)d_in[6];
    const float* be1 = (const float*)d_in[7];
    const float* g2  = (const float*)d_in[8];
    const float* be2 = (const float*)d_in[9];
    const float* W1  = (const float*)d_in[10];
    const float* b1  = (const float*)d_in[11];
    const float* W2  = (const float*)d_in[12];
    const float* b2  = (const float*)d_in[13];

    const int T = 2048, M = 4 * T;  // 8192 rows
    const size_t MB = 1ull << 20;
    char* ws = (char*)d_ws;

    // workspace map (128 MB, live-range overlays):
    bf16*  xn    = (bf16*)(ws + 0 * MB);     // 16 MB; later: attnb; later: hb
    bf16*  qkv   = (bf16*)(ws + 16 * MB);    // 48 MB [M][3072]; later: hb tail
    bf16*  vt    = (bf16*)(ws + 64 * MB);    // 16 MB [b*16+h][64][T]
    bf16*  wqkvt = (bf16*)(ws + 80 * MB);    //  6 MB [3072][1024]; later: x1b
    bf16*  x1b   = (bf16*)(ws + 80 * MB);    // 16 MB [M][1024] bf16 residual
    bf16*  wot   = (bf16*)(ws + 96 * MB);    //  2 MB; later: xn2
    bf16*  xn2   = (bf16*)(ws + 96 * MB);    // 16 MB
    bf16*  w1t   = (bf16*)(ws + 112 * MB);   //  8 MB [4096][1024]
    bf16*  w2t   = (bf16*)(ws + 120 * MB);   //  8 MB [1024][4096]
    bf16*  attnb = (bf16*)(ws + 0 * MB);
    bf16*  hb    = (bf16*)(ws + 0 * MB);     // 64 MB [M][4096]

    dim3 blk(256);

    prep_weights<<<12288, blk, 0, stream>>>(Wq, Wk, Wv, Wo, W1, W2,
                                            wqkvt, wot, w1t, w2t);

    ln_kernel<float><<<M, blk, 0, stream>>>(x, g1, be1, xn);

    gemm_bt<false, false, false, float, bf16><<<dim3(24, 64), blk, 0, stream>>>(
        xn, 1024, wqkvt, 1024, nullptr, nullptr, 0, qkv, 3072, M, 3072, 1024);

    vt_kernel<<<dim3(2, T / 32, 64), blk, 0, stream>>>(qkv, vt, T);

    attn_kernel<<<dim3(T / 128, 16, 4), dim3(512), 0, stream>>>(qkv, vt, attnb, T);

    gemm_bt<false, true, true, float, bf16><<<dim3(8, 64), blk, 0, stream>>>(
        attnb, 1024, wot, 1024, bo, x, 1024, x1b, 1024, M, 1024, 1024);

    ln_kernel<bf16><<<M, blk, 0, stream>>>(x1b, g2, be2, xn2);

    gemm_bt<true, true, false, float, bf16><<<dim3(32, 64), blk, 0, stream>>>(
        xn2, 1024, w1t, 1024, b1, nullptr, 0, hb, 4096, M, 4096, 1024);

    gemm_bt<false, true, true, bf16, float><<<dim3(8, 64), blk, 0, stream>>>(
        hb, 4096, w2t, 4096, b2, x1b, 1024, (float*)d_out, 1024, M, 1024, 4096);
}

// Round 2
// 504.781 us; speedup vs baseline: 1.1207x; 1.0584x over previous
//
#include <hip/hip_runtime.h>
#include <hip/hip_bf16.h>

typedef __hip_bfloat16 bf16;
typedef __attribute__((ext_vector_type(8))) short bf16x8;
typedef __attribute__((ext_vector_type(4))) short s16x4;
typedef __attribute__((ext_vector_type(4))) float f32x4;

__device__ __forceinline__ float b2f(bf16 v) { return __bfloat162float(v); }
__device__ __forceinline__ bf16  f2b(float v) { return __float2bfloat16(v); }
__device__ __forceinline__ float ldf(const bf16* p)  { return __bfloat162float(*p); }
__device__ __forceinline__ float ldf(const float* p) { return *p; }
__device__ __forceinline__ void  stf(bf16* p, float v)  { *p = __float2bfloat16(v); }
__device__ __forceinline__ void  stf(float* p, float v) { *p = v; }

// async global->LDS, 16 B per lane; LDS dest = wave-uniform base + lane*16
__device__ __forceinline__ void load_lds16(const bf16* g, short* lds) {
    __builtin_amdgcn_global_load_lds(
        (const __attribute__((address_space(1))) unsigned int*)g,
        (__attribute__((address_space(3))) unsigned int*)lds, 16, 0, 0);
}

// ---------------------------------------------------------------------------
// LayerNorm over last dim C=1024. One block (256 threads) per row. bf16 out.
// ---------------------------------------------------------------------------
template<typename InT>
__global__ __launch_bounds__(256) void ln_kernel(const InT* __restrict__ x,
                                                 const float* __restrict__ g,
                                                 const float* __restrict__ b,
                                                 bf16* __restrict__ out)
{
    const int C = 1024;
    int row = blockIdx.x;
    int tid = threadIdx.x;
    const InT* xr = x + (size_t)row * C;

    float v[4];
    float s = 0.f, s2 = 0.f;
#pragma unroll
    for (int i = 0; i < 4; ++i) {
        float f = ldf(xr + tid + i * 256);
        v[i] = f; s += f; s2 += f * f;
    }
#pragma unroll
    for (int off = 32; off > 0; off >>= 1) {
        s  += __shfl_down(s,  off, 64);
        s2 += __shfl_down(s2, off, 64);
    }
    __shared__ float red[8];
    int wave = tid >> 6;
    if ((tid & 63) == 0) { red[wave] = s; red[wave + 4] = s2; }
    __syncthreads();
    float ts  = red[0] + red[1] + red[2] + red[3];
    float ts2 = red[4] + red[5] + red[6] + red[7];
    float mu  = ts * (1.f / 1024.f);
    float var = ts2 * (1.f / 1024.f) - mu * mu;
    float rstd = rsqrtf(var + 1e-5f);
#pragma unroll
    for (int i = 0; i < 4; ++i) {
        int c = tid + i * 256;
        out[(size_t)row * C + c] = f2b((v[i] - mu) * rstd * g[c] + b[c]);
    }
}

// ---------------------------------------------------------------------------
// All six weight transposes (fp32 -> bf16, out[n][k] = in[k][n]) in ONE
// kernel. Flat tile id selects matrix + 32x32 tile.
// ---------------------------------------------------------------------------
__global__ __launch_bounds__(256) void prep_weights(
    const float* __restrict__ Wq, const float* __restrict__ Wk,
    const float* __restrict__ Wv, const float* __restrict__ Wo,
    const float* __restrict__ W1, const float* __restrict__ W2,
    bf16* __restrict__ wqkvt, bf16* __restrict__ wot,
    bf16* __restrict__ w1t, bf16* __restrict__ w2t)
{
    __shared__ float t[32][33];
    int tx = threadIdx.x & 31, ty = threadIdx.x >> 5;
    int id = blockIdx.x;
    const float* in; bf16* out; int in_ld, out_ld, n0, k0;
    if (id < 3072) {
        const float* Ws[3] = {Wq, Wk, Wv};
        int m = id >> 10, r = id & 1023;
        int z = r >> 6, rt = r & 63;
        in = Ws[m] + z * 65536;                       // [1024][64]
        out = wqkvt + (size_t)(m * 1024 + z * 64) * 1024;
        in_ld = 64; out_ld = 1024;
        n0 = (rt & 1) * 32; k0 = (rt >> 1) * 32;
    } else if (id < 4096) {
        int r = id - 3072;
        in = Wo; out = wot; in_ld = 1024; out_ld = 1024;
        n0 = (r & 31) * 32; k0 = (r >> 5) * 32;
    } else if (id < 8192) {
        int r = id - 4096;
        in = W1; out = w1t; in_ld = 4096; out_ld = 1024;
        n0 = (r & 127) * 32; k0 = (r >> 7) * 32;
    } else {
        int r = id - 8192;
        in = W2; out = w2t; in_ld = 1024; out_ld = 4096;
        n0 = (r & 31) * 32; k0 = (r >> 5) * 32;
    }
#pragma unroll
    for (int i = 0; i < 4; ++i)
        t[ty + i * 8][tx] = in[(size_t)(k0 + ty + i * 8) * in_ld + n0 + tx];
    __syncthreads();
#pragma unroll
    for (int i = 0; i < 4; ++i)
        out[(size_t)(n0 + ty + i * 8) * out_ld + k0 + tx] = f2b(t[tx][ty + i * 8]);
}

// ---------------------------------------------------------------------------
// V^T: vt[(b*16+h)*64 + d][t] = qkv[(b*T+t)*3072 + 2048 + h*64 + d]
// ---------------------------------------------------------------------------
__global__ __launch_bounds__(256) void vt_kernel(
    const bf16* __restrict__ qkv, bf16* __restrict__ vt, int T)
{
    __shared__ float t[32][33];
    int tx = threadIdx.x & 31, ty = threadIdx.x >> 5;
    int z = blockIdx.z, b = z >> 4, h = z & 15;
    const bf16* in = qkv + (size_t)b * T * 3072 + 2048 + h * 64;  // [t][d] ld 3072
    bf16* out = vt + (size_t)z * 64 * T;                          // [d][t] ld T
    int n0 = blockIdx.x * 32, k0 = blockIdx.y * 32;
#pragma unroll
    for (int i = 0; i < 4; ++i)
        t[ty + i * 8][tx] = b2f(in[(size_t)(k0 + ty + i * 8) * 3072 + n0 + tx]);
    __syncthreads();
#pragma unroll
    for (int i = 0; i < 4; ++i)
        out[(size_t)(n0 + ty + i * 8) * T + k0 + tx] = f2b(t[tx][ty + i * 8]);
}

// ---------------------------------------------------------------------------
// MFMA GEMM: C[M,N] = A[M,K] @ B[K,N], B given TRANSPOSED (Bt[n][k]).
// 128x128 tile, BK=32, 256 thr = 4 waves. XOR-swizzled LDS fragments.
// Double-buffered LDS, stage(t+1) issued BEFORE compute of tile t, ONE
// __syncthreads per K-step (its implicit vmcnt(0) drain is the prefetch wait).
// XCD-aware block remap: flat id -> (by = f % nby, bx = f / nby).
// ---------------------------------------------------------------------------
template<bool RELU, bool HAS_BIAS, bool HAS_RES, typename ResT, typename OutT>
__global__ __launch_bounds__(256) void gemm_bt(
    const bf16* __restrict__ A, int lda,
    const bf16* __restrict__ Bt, int ldb,
    const float* __restrict__ bias,
    const ResT* __restrict__ res, int ldr,
    OutT* __restrict__ Cm, int ldc,
    int M, int N, int K)
{
    __shared__ short As[2][128 * 32];
    __shared__ short Bs[2][128 * 32];
    int tid = threadIdx.x, wv = tid >> 6, ln = tid & 63;

    // XCD-locality remap (see header comment)
    int f = blockIdx.x + blockIdx.y * gridDim.x;
    int nby = gridDim.y;
    int by = f % nby, bx = f / nby;
    int bm0 = by * 128, bn0 = bx * 128;

    int wm = (wv & 1) * 64, wn = (wv >> 1) * 64;
    int quad = ln >> 4, lane15 = ln & 15;

    f32x4 acc[4][4] = {};

    int srow = ln >> 2;                              // row within 16-row chunk
    int scol = (((ln & 3) ^ (srow & 3)) * 8);        // swizzled source col
    int sw   = (quad ^ (lane15 & 3)) * 8;            // swizzled read slot
    const bf16* Ab = A + (size_t)bm0 * lda;
    const bf16* Bb = Bt + (size_t)bn0 * ldb;

    // prologue: stage tile 0 into buffer 0
#pragma unroll
    for (int i = 0; i < 2; ++i) {
        int ch = wv + i * 4;
        load_lds16(Ab + (size_t)(ch * 16 + srow) * lda + scol, &As[0][ch * 16 * 32]);
        load_lds16(Bb + (size_t)(ch * 16 + srow) * ldb + scol, &Bs[0][ch * 16 * 32]);
    }
    __syncthreads();   // drains vmcnt -> tile 0 resident

    int cur = 0;
    for (int k0 = 0; k0 < K; k0 += 32) {
        // issue prefetch of tile t+1 into the other buffer (async, vmcnt)
        if (k0 + 32 < K) {
            int nb = cur ^ 1;
#pragma unroll
            for (int i = 0; i < 2; ++i) {
                int ch = wv + i * 4;
                load_lds16(Ab + (size_t)(ch * 16 + srow) * lda + k0 + 32 + scol,
                           &As[nb][ch * 16 * 32]);
                load_lds16(Bb + (size_t)(ch * 16 + srow) * ldb + k0 + 32 + scol,
                           &Bs[nb][ch * 16 * 32]);
            }
        }
        bf16x8 af[4], bfr[4];
#pragma unroll
        for (int mi = 0; mi < 4; ++mi)
            af[mi] = *(const bf16x8*)&As[cur][(wm + mi * 16 + lane15) * 32 + sw];
#pragma unroll
        for (int ni = 0; ni < 4; ++ni)
            bfr[ni] = *(const bf16x8*)&Bs[cur][(wn + ni * 16 + lane15) * 32 + sw];
#pragma unroll
        for (int mi = 0; mi < 4; ++mi)
#pragma unroll
            for (int ni = 0; ni < 4; ++ni)
                acc[mi][ni] = __builtin_amdgcn_mfma_f32_16x16x32_bf16(
                    af[mi], bfr[ni], acc[mi][ni], 0, 0, 0);
        __syncthreads();   // drains vmcnt: tile t+1 resident; reads of cur done
        cur ^= 1;
    }

#pragma unroll
    for (int mi = 0; mi < 4; ++mi) {
#pragma unroll
        for (int r = 0; r < 4; ++r) {
            int gm = bm0 + wm + mi * 16 + quad * 4 + r;
#pragma unroll
            for (int ni = 0; ni < 4; ++ni) {
                int gn = bn0 + wn + ni * 16 + lane15;
                float v = acc[mi][ni][r];
                if (HAS_BIAS) v += bias[gn];
                if (HAS_RES)  v += ldf(res + (size_t)gm * ldr + gn);
                if (RELU)     v = fmaxf(v, 0.f);
                stf(Cm + (size_t)gm * ldc + gn, v);
            }
        }
    }
}

// ---------------------------------------------------------------------------
// One q-tile's work for one 64-key tile: QK^T (S^T form), online softmax in
// exp2 domain, P->LDS (wave-private), PV. All state per-lane/per-wave.
// ---------------------------------------------------------------------------
__device__ __forceinline__ void attn_tile_q(
    const short* __restrict__ Ks, const short* __restrict__ Vs,
    short* __restrict__ Psw,
    const bf16x8* qf, f32x4* oacc, float& mrun, float& lrun,
    int ktbase, int qmin, int quad, int lane15, int r7)
{
    const float scale2 = 0.18033688011112042f;   // (1/8) * log2(e)
    const int PS = 72;
    f32x4 sacc[4] = {};
    __builtin_amdgcn_s_setprio(1);
#pragma unroll
    for (int ks = 0; ks < 2; ++ks) {
        int so = ((ks * 4 + quad) ^ r7) * 8;
#pragma unroll
        for (int mi = 0; mi < 4; ++mi) {
            bf16x8 kf = *(const bf16x8*)&Ks[(mi * 16 + lane15) * 64 + so];
            sacc[mi] = __builtin_amdgcn_mfma_f32_16x16x32_bf16(kf, qf[ks], sacc[mi], 0, 0, 0);
        }
    }
    __builtin_amdgcn_s_setprio(0);

    // causal mask (only diagonal-crossing tiles)
    if (ktbase + 63 > qmin) {
        int ql = qmin + lane15;
#pragma unroll
        for (int mi = 0; mi < 4; ++mi)
#pragma unroll
            for (int r = 0; r < 4; ++r)
                if (ktbase + mi * 16 + quad * 4 + r > ql) sacc[mi][r] = -3e38f;
    }

    // row max (16 keys in-lane, cross-quad reduce)
    float mx = sacc[0][0];
#pragma unroll
    for (int mi = 0; mi < 4; ++mi)
#pragma unroll
        for (int r = 0; r < 4; ++r) mx = fmaxf(mx, sacc[mi][r]);
    mx = fmaxf(mx, __shfl_xor(mx, 16, 64));
    mx = fmaxf(mx, __shfl_xor(mx, 32, 64));
    float pmax = mx * scale2;

    // T13 defer-max (threshold 11.5 log2-units ~= e^8)
    if (!__all(pmax <= mrun + 11.5f)) {
        float mn = fmaxf(mrun, pmax);
        float alpha = exp2f(mrun - mn);
        mrun = mn;
        lrun *= alpha;
#pragma unroll
        for (int di = 0; di < 4; ++di)
#pragma unroll
            for (int r = 0; r < 4; ++r) oacc[di][r] *= alpha;
    }

    float psum = 0.f;
#pragma unroll
    for (int mi = 0; mi < 4; ++mi) {
        float p[4];
#pragma unroll
        for (int r = 0; r < 4; ++r) {
            p[r] = exp2f(fmaf(sacc[mi][r], scale2, -mrun));
            psum += p[r];
        }
        short tmp[4];
#pragma unroll
        for (int r = 0; r < 4; ++r) {
            bf16 pb = f2b(p[r]);
            tmp[r] = *(short*)&pb;
        }
        *(s16x4*)&Psw[lane15 * PS + mi * 16 + quad * 4] = *(s16x4*)tmp;
    }
    lrun += psum;

    // O^T += V^T P^T  (wave-private Psw: no barrier needed)
    __builtin_amdgcn_s_setprio(1);
#pragma unroll
    for (int ks = 0; ks < 2; ++ks) {
        int so = ((ks * 4 + quad) ^ r7) * 8;
        bf16x8 pf = *(const bf16x8*)&Psw[lane15 * PS + ks * 32 + quad * 8];
#pragma unroll
        for (int di = 0; di < 4; ++di) {
            bf16x8 vf = *(const bf16x8*)&Vs[(di * 16 + lane15) * 64 + so];
            oacc[di] = __builtin_amdgcn_mfma_f32_16x16x32_bf16(vf, pf, oacc[di], 0, 0, 0);
        }
    }
    __builtin_amdgcn_s_setprio(0);
}

// ---------------------------------------------------------------------------
// MFMA causal flash attention, S^T form, 512 thr = 8 waves.
// CAUSAL-BALANCED DUAL Q-TILE: block bx processes q-tiles (15-bx, bx) in ONE
// k-loop sharing K/V staging. Every block does exactly 34 tile-units ->
// uniform duration, 512 blocks = 2/CU all co-resident, no dispatch tail.
// Dual-active iterations give 2x independent MFMA+softmax chains per barrier
// (T15 overlap). K/V double-buffered, prefetch 1 tile ahead.
// ---------------------------------------------------------------------------
__global__ __launch_bounds__(512, 4) void attn_kernel(
    const bf16* __restrict__ qkv, const bf16* __restrict__ vt,
    bf16* __restrict__ o, int T)
{
    const int LDQ = 3072;
    const int PS = 72;   // Ps row stride (shorts): 144 B, 16B-aligned
    int bx = blockIdx.x;
    int qta = 15 - bx;                 // heavy tile (processed first)
    int qtb = bx;                      // light tile (shares K/V range prefix)
    int h = blockIdx.y, b = blockIdx.z;
    int tid = threadIdx.x, wv = tid >> 6, ln = tid & 63;
    int quad = ln >> 4, lane15 = ln & 15, r7 = lane15 & 7;

    __shared__ short KV[2][2][64 * 64];   // [buf][0=K [key][d], 1=V [d][key]]
    __shared__ short Ps[2][8][16 * PS];   // [qtile][wave][qrow16][key64]

    int lr = ln >> 3;                     // 0..7: row within 8-row chunk
    int lc = ((ln & 7) ^ lr) * 8;         // swizzled source col offset

    const bf16* kbase = qkv + (size_t)(b * T) * LDQ + 1024 + h * 64;
    const bf16* vbase = vt + (size_t)((b * 16 + h) * 64) * T;

    // ---- stage BOTH Q tiles (each 128x64) into the KV area, read to regs
#pragma unroll
    for (int i = 0; i < 2; ++i) {
        int ch = wv * 2 + i;
        load_lds16(qkv + (size_t)(b * T + qta * 128 + ch * 8 + lr) * LDQ + h * 64 + lc,
                   &KV[0][0][ch * 512]);
        load_lds16(qkv + (size_t)(b * T + qtb * 128 + ch * 8 + lr) * LDQ + h * 64 + lc,
                   &KV[1][0][ch * 512]);
    }
    __syncthreads();   // Q staged (vmcnt drained by barrier)
    bf16x8 qfa[2], qfb[2];
#pragma unroll
    for (int ks = 0; ks < 2; ++ks) {
        int off = (wv * 16 + lane15) * 64 + (((ks * 4 + quad) ^ r7) * 8);
        qfa[ks] = *(const bf16x8*)&KV[0][0][off];
        qfb[ks] = *(const bf16x8*)&KV[1][0][off];
    }
    __syncthreads();   // all Q reads done before K/V overwrite

    f32x4 oacca[4] = {}, oaccb[4] = {};
    float mra = -1e30f, lra = 0.f, mrb = -1e30f, lrb = 0.f;
    int qmina = qta * 128 + wv * 16;
    int qminb = qtb * 128 + wv * 16;
    int ntiles = 2 * qta + 2;

    // prefetch tile 0 into buf 0 (wave wv stages rows wv*8..wv*8+7)
    load_lds16(kbase + (size_t)(wv * 8 + lr) * LDQ + lc, &KV[0][0][wv * 8 * 64]);
    load_lds16(vbase + (size_t)(wv * 8 + lr) * T + lc, &KV[0][1][wv * 8 * 64]);

    for (int kt = 0; kt < ntiles; ++kt) {
        __syncthreads();   // tile kt published (barrier drains vmcnt)
        if (kt + 1 < ntiles) {
            int nb = (kt + 1) & 1;
            load_lds16(kbase + (size_t)((kt + 1) * 64 + wv * 8 + lr) * LDQ + lc,
                       &KV[nb][0][wv * 8 * 64]);
            load_lds16(vbase + (size_t)(wv * 8 + lr) * T + (kt + 1) * 64 + lc,
                       &KV[nb][1][wv * 8 * 64]);
        }
        const short* Ks = &KV[kt & 1][0][0];
        const short* Vs = &KV[kt & 1][1][0];
        int kb = kt * 64;

        if (kb <= qmina + 15)
            attn_tile_q(Ks, Vs, &Ps[0][wv][0], qfa, oacca, mra, lra,
                        kb, qmina, quad, lane15, r7);
        if (kb <= qminb + 15)
            attn_tile_q(Ks, Vs, &Ps[1][wv][0], qfb, oaccb, mrb, lrb,
                        kb, qminb, quad, lane15, r7);
    }

    // ---- epilogue: cross-quad l reduce + store, both q-tiles
    lra += __shfl_xor(lra, 16, 64);
    lra += __shfl_xor(lra, 32, 64);
    float inva = 1.f / lra;
    size_t rowa = (size_t)(b * T + qta * 128 + wv * 16 + lane15);
#pragma unroll
    for (int di = 0; di < 4; ++di) {
        short tmp[4];
#pragma unroll
        for (int r = 0; r < 4; ++r) {
            bf16 ob = f2b(oacca[di][r] * inva);
            tmp[r] = *(short*)&ob;
        }
        *(s16x4*)&o[rowa * 1024 + h * 64 + di * 16 + quad * 4] = *(s16x4*)tmp;
    }

    lrb += __shfl_xor(lrb, 16, 64);
    lrb += __shfl_xor(lrb, 32, 64);
    float invb = 1.f / lrb;
    size_t rowb = (size_t)(b * T + qtb * 128 + wv * 16 + lane15);
#pragma unroll
    for (int di = 0; di < 4; ++di) {
        short tmp[4];
#pragma unroll
        for (int r = 0; r < 4; ++r) {
            bf16 ob = f2b(oaccb[di][r] * invb);
            tmp[r] = *(short*)&ob;
        }
        *(s16x4*)&o[rowb * 1024 + h * 64 + di * 16 + quad * 4] = *(s16x4*)tmp;
    }
}

// ---------------------------------------------------------------------------
extern "C" void kernel_launch(void* const* d_in, const int* in_sizes, int n_in,
                              void* d_out, int out_size, void* d_ws, size_t ws_size,
                              hipStream_t stream)
{
    (void)in_sizes; (void)n_in; (void)out_size; (void)ws_size;
    const float* x   = (const float*)d_in[0];
    const float* Wq  = (const float*)d_in[1];
    const float* Wk  = (const float*)d_in[2];
    const float* Wv  = (const float*)d_in[3];
    const float* Wo  = (const float*)d_in[4];
    const float* bo  = (const float*)d_in[5];
    const float* g1  = (const float*)d_in[6];
    const float* be1 = (const float*)d_in[7];
    const float* g2  = (const float*)d_in[8];
    const float* be2 = (const float*)d_in[9];
    const float* W1  = (const float*)d_in[10];
    const float* b1  = (const float*)d_in[11];
    const float* W2  = (const float*)d_in[12];
    const float* b2  = (const float*)d_in[13];

    const int T = 2048, M = 4 * T;  // 8192 rows
    const size_t MB = 1ull << 20;
    char* ws = (char*)d_ws;

    // workspace map (128 MB, live-range overlays):
    bf16*  xn    = (bf16*)(ws + 0 * MB);     // 16 MB; later: attnb; later: hb
    bf16*  qkv   = (bf16*)(ws + 16 * MB);    // 48 MB [M][3072]; later: hb tail
    bf16*  vt    = (bf16*)(ws + 64 * MB);    // 16 MB [b*16+h][64][T]
    bf16*  wqkvt = (bf16*)(ws + 80 * MB);    //  6 MB [3072][1024]; later: x1b
    bf16*  x1b   = (bf16*)(ws + 80 * MB);    // 16 MB [M][1024] bf16 residual
    bf16*  wot   = (bf16*)(ws + 96 * MB);    //  2 MB; later: xn2
    bf16*  xn2   = (bf16*)(ws + 96 * MB);    // 16 MB
    bf16*  w1t   = (bf16*)(ws + 112 * MB);   //  8 MB [4096][1024]
    bf16*  w2t   = (bf16*)(ws + 120 * MB);   //  8 MB [1024][4096]
    bf16*  attnb = (bf16*)(ws + 0 * MB);
    bf16*  hb    = (bf16*)(ws + 0 * MB);     // 64 MB [M][4096]

    dim3 blk(256);

    prep_weights<<<12288, blk, 0, stream>>>(Wq, Wk, Wv, Wo, W1, W2,
                                            wqkvt, wot, w1t, w2t);

    ln_kernel<float><<<M, blk, 0, stream>>>(x, g1, be1, xn);

    gemm_bt<false, false, false, float, bf16><<<dim3(24, 64), blk, 0, stream>>>(
        xn, 1024, wqkvt, 1024, nullptr, nullptr, 0, qkv, 3072, M, 3072, 1024);

    vt_kernel<<<dim3(2, T / 32, 64), blk, 0, stream>>>(qkv, vt, T);

    attn_kernel<<<dim3(8, 16, 4), dim3(512), 0, stream>>>(qkv, vt, attnb, T);

    gemm_bt<false, true, true, float, bf16><<<dim3(8, 64), blk, 0, stream>>>(
        attnb, 1024, wot, 1024, bo, x, 1024, x1b, 1024, M, 1024, 1024);

    ln_kernel<bf16><<<M, blk, 0, stream>>>(x1b, g2, be2, xn2);

    gemm_bt<true, true, false, float, bf16><<<dim3(32, 64), blk, 0, stream>>>(
        xn2, 1024, w1t, 1024, b1, nullptr, 0, hb, 4096, M, 4096, 1024);

    gemm_bt<false, true, true, bf16, float><<<dim3(8, 64), blk, 0, stream>>>(
        hb, 4096, w2t, 4096, b2, x1b, 1024, (float*)d_out, 1024, M, 1024, 4096);
}

// Round 3
// 488.271 us; speedup vs baseline: 1.1586x; 1.0338x over previous
//
#include <hip/hip_runtime.h>
#include <hip/hip_bf16.h>

typedef __hip_bfloat16 bf16;
typedef __attribute__((ext_vector_type(8))) short bf16x8;
typedef __attribute__((ext_vector_type(4))) short s16x4;
typedef __attribute__((ext_vector_type(4))) float f32x4;

__device__ __forceinline__ float b2f(bf16 v) { return __bfloat162float(v); }
__device__ __forceinline__ bf16  f2b(float v) { return __float2bfloat16(v); }
__device__ __forceinline__ float ldf(const bf16* p)  { return __bfloat162float(*p); }
__device__ __forceinline__ float ldf(const float* p) { return *p; }
__device__ __forceinline__ void  stf(bf16* p, float v)  { *p = __float2bfloat16(v); }
__device__ __forceinline__ void  stf(float* p, float v) { *p = v; }

// vectorized 4-element row loads for LayerNorm
__device__ __forceinline__ void ld4(const float* p, float* v) {
    float4 t = *(const float4*)p;
    v[0] = t.x; v[1] = t.y; v[2] = t.z; v[3] = t.w;
}
__device__ __forceinline__ void ld4(const bf16* p, float* v) {
    s16x4 t = *(const s16x4*)p;
#pragma unroll
    for (int j = 0; j < 4; ++j) { short s = t[j]; v[j] = b2f(*(bf16*)&s); }
}

// async global->LDS, 16 B per lane; LDS dest = wave-uniform base + lane*16
__device__ __forceinline__ void load_lds16(const bf16* g, short* lds) {
    __builtin_amdgcn_global_load_lds(
        (const __attribute__((address_space(1))) unsigned int*)g,
        (__attribute__((address_space(3))) unsigned int*)lds, 16, 0, 0);
}

// ---------------------------------------------------------------------------
// LayerNorm over last dim C=1024. One block (256 threads) per row. bf16 out.
// Vectorized: thread t owns contiguous elems [4t, 4t+4) (16B fp32 / 8B bf16).
// ---------------------------------------------------------------------------
template<typename InT>
__global__ __launch_bounds__(256) void ln_kernel(const InT* __restrict__ x,
                                                 const float* __restrict__ g,
                                                 const float* __restrict__ b,
                                                 bf16* __restrict__ out)
{
    const int C = 1024;
    int row = blockIdx.x;
    int tid = threadIdx.x;
    const InT* xr = x + (size_t)row * C;

    float v[4];
    ld4(xr + tid * 4, v);
    float s = 0.f, s2 = 0.f;
#pragma unroll
    for (int i = 0; i < 4; ++i) { s += v[i]; s2 += v[i] * v[i]; }
#pragma unroll
    for (int off = 32; off > 0; off >>= 1) {
        s  += __shfl_down(s,  off, 64);
        s2 += __shfl_down(s2, off, 64);
    }
    __shared__ float red[8];
    int wave = tid >> 6;
    if ((tid & 63) == 0) { red[wave] = s; red[wave + 4] = s2; }
    __syncthreads();
    float ts  = red[0] + red[1] + red[2] + red[3];
    float ts2 = red[4] + red[5] + red[6] + red[7];
    float mu  = ts * (1.f / 1024.f);
    float var = ts2 * (1.f / 1024.f) - mu * mu;
    float rstd = rsqrtf(var + 1e-5f);

    float4 gg = *(const float4*)(g + tid * 4);
    float4 bb = *(const float4*)(b + tid * 4);
    float gj[4] = {gg.x, gg.y, gg.z, gg.w};
    float bj[4] = {bb.x, bb.y, bb.z, bb.w};
    s16x4 o4;
#pragma unroll
    for (int j = 0; j < 4; ++j) {
        bf16 ob = f2b((v[j] - mu) * rstd * gj[j] + bj[j]);
        o4[j] = *(short*)&ob;
    }
    *(s16x4*)(out + (size_t)row * C + tid * 4) = o4;
}

// ---------------------------------------------------------------------------
// All six weight transposes (fp32 -> bf16, out[n][k] = in[k][n]) in ONE
// kernel. Flat tile id selects matrix + 32x32 tile.
// ---------------------------------------------------------------------------
__global__ __launch_bounds__(256) void prep_weights(
    const float* __restrict__ Wq, const float* __restrict__ Wk,
    const float* __restrict__ Wv, const float* __restrict__ Wo,
    const float* __restrict__ W1, const float* __restrict__ W2,
    bf16* __restrict__ wqkvt, bf16* __restrict__ wot,
    bf16* __restrict__ w1t, bf16* __restrict__ w2t)
{
    __shared__ float t[32][33];
    int tx = threadIdx.x & 31, ty = threadIdx.x >> 5;
    int id = blockIdx.x;
    const float* in; bf16* out; int in_ld, out_ld, n0, k0;
    if (id < 3072) {
        const float* Ws[3] = {Wq, Wk, Wv};
        int m = id >> 10, r = id & 1023;
        int z = r >> 6, rt = r & 63;
        in = Ws[m] + z * 65536;                       // [1024][64]
        out = wqkvt + (size_t)(m * 1024 + z * 64) * 1024;
        in_ld = 64; out_ld = 1024;
        n0 = (rt & 1) * 32; k0 = (rt >> 1) * 32;
    } else if (id < 4096) {
        int r = id - 3072;
        in = Wo; out = wot; in_ld = 1024; out_ld = 1024;
        n0 = (r & 31) * 32; k0 = (r >> 5) * 32;
    } else if (id < 8192) {
        int r = id - 4096;
        in = W1; out = w1t; in_ld = 4096; out_ld = 1024;
        n0 = (r & 127) * 32; k0 = (r >> 7) * 32;
    } else {
        int r = id - 8192;
        in = W2; out = w2t; in_ld = 1024; out_ld = 4096;
        n0 = (r & 31) * 32; k0 = (r >> 5) * 32;
    }
#pragma unroll
    for (int i = 0; i < 4; ++i)
        t[ty + i * 8][tx] = in[(size_t)(k0 + ty + i * 8) * in_ld + n0 + tx];
    __syncthreads();
#pragma unroll
    for (int i = 0; i < 4; ++i)
        out[(size_t)(n0 + ty + i * 8) * out_ld + k0 + tx] = f2b(t[tx][ty + i * 8]);
}

// ---------------------------------------------------------------------------
// V^T: vt[(b*16+h)*64 + d][t] = qkv[(b*T+t)*3072 + 2048 + h*64 + d]
// ---------------------------------------------------------------------------
__global__ __launch_bounds__(256) void vt_kernel(
    const bf16* __restrict__ qkv, bf16* __restrict__ vt, int T)
{
    __shared__ float t[32][33];
    int tx = threadIdx.x & 31, ty = threadIdx.x >> 5;
    int z = blockIdx.z, b = z >> 4, h = z & 15;
    const bf16* in = qkv + (size_t)b * T * 3072 + 2048 + h * 64;  // [t][d] ld 3072
    bf16* out = vt + (size_t)z * 64 * T;                          // [d][t] ld T
    int n0 = blockIdx.x * 32, k0 = blockIdx.y * 32;
#pragma unroll
    for (int i = 0; i < 4; ++i)
        t[ty + i * 8][tx] = b2f(in[(size_t)(k0 + ty + i * 8) * 3072 + n0 + tx]);
    __syncthreads();
#pragma unroll
    for (int i = 0; i < 4; ++i)
        out[(size_t)(n0 + ty + i * 8) * T + k0 + tx] = f2b(t[tx][ty + i * 8]);
}

// ---------------------------------------------------------------------------
// MFMA GEMM: C[M,N] = A[M,K] @ B[K,N], B given TRANSPOSED (Bt[n][k]).
// 128x128 tile, 256 thr = 4 waves, templated BK (32 or 64).
// Double-buffered LDS; stage(t+1) issued BEFORE compute of tile t; ONE
// __syncthreads per K-step (its implicit vmcnt(0) drain is the prefetch wait).
// Swizzle (BK=32): slot = slot_g ^ ((row>>1)&3) -> wave read is 2-way
//   (free) instead of the old 4-way (row&3 collided for lane15 = {0,4,8,12}).
// Swizzle (BK=64): 128-B rows, 8 slots: slot = slot_g ^ (row&7) -> 2-way.
// BK=64 halves barrier count (32 MFMA/wave per barrier) -- used for the
// K=4096 FFN2 GEMM where barrier amortization dominates. LDS 64 KB -> 2
// blocks/CU there (grid 512 = exactly 2/CU).
// XCD-aware block remap: flat id -> (by = f % nby, bx = f / nby).
// ---------------------------------------------------------------------------
template<int BK, bool RELU, bool HAS_BIAS, bool HAS_RES, typename ResT, typename OutT>
__global__ __launch_bounds__(256) void gemm_bt(
    const bf16* __restrict__ A, int lda,
    const bf16* __restrict__ Bt, int ldb,
    const float* __restrict__ bias,
    const ResT* __restrict__ res, int ldr,
    OutT* __restrict__ Cm, int ldc,
    int M, int N, int K)
{
    __shared__ short As[2][128 * BK];
    __shared__ short Bs[2][128 * BK];
    int tid = threadIdx.x, wv = tid >> 6, ln = tid & 63;

    // XCD-locality remap (see header comment)
    int f = blockIdx.x + blockIdx.y * gridDim.x;
    int nby = gridDim.y;
    int by = f % nby, bx = f / nby;
    int bm0 = by * 128, bn0 = bx * 128;

    int wm = (wv & 1) * 64, wn = (wv >> 1) * 64;
    int quad = ln >> 4, lane15 = ln & 15;

    f32x4 acc[4][4] = {};

    const bf16* Ab = A + (size_t)bm0 * lda;
    const bf16* Bb = Bt + (size_t)bn0 * ldb;

    auto stage = [&](int buf, int kk) {
        if constexpr (BK == 32) {
            // 2 chunks x (16 rows x 4 slots of 16B); src col pre-swizzled
            int srow = ln >> 2;
            int scol = (((ln & 3) ^ ((ln >> 3) & 3)) * 8);
#pragma unroll
            for (int i = 0; i < 2; ++i) {
                int ch = wv + i * 4;
                load_lds16(Ab + (size_t)(ch * 16 + srow) * lda + kk + scol,
                           &As[buf][ch * 16 * 32]);
                load_lds16(Bb + (size_t)(ch * 16 + srow) * ldb + kk + scol,
                           &Bs[buf][ch * 16 * 32]);
            }
        } else {
            // 4 chunks x (32 rows x 8 slots of 16B); src col pre-swizzled
            int srow = ln >> 3;                 // 0..7 (row within wave group)
            int scol = ((ln & 7) ^ srow) * 8;
#pragma unroll
            for (int i = 0; i < 4; ++i) {
                int r0 = i * 32 + wv * 8;
                load_lds16(Ab + (size_t)(r0 + srow) * lda + kk + scol,
                           &As[buf][r0 * 64]);
                load_lds16(Bb + (size_t)(r0 + srow) * ldb + kk + scol,
                           &Bs[buf][r0 * 64]);
            }
        }
    };

    // prologue: stage tile 0 into buffer 0
    stage(0, 0);
    __syncthreads();   // drains vmcnt -> tile 0 resident

    int cur = 0;
    for (int k0 = 0; k0 < K; k0 += BK) {
        if (k0 + BK < K) stage(cur ^ 1, k0 + BK);
        if constexpr (BK == 32) {
            int sw = (quad ^ ((lane15 >> 1) & 3)) * 8;
            bf16x8 af[4], bfr[4];
#pragma unroll
            for (int mi = 0; mi < 4; ++mi)
                af[mi] = *(const bf16x8*)&As[cur][(wm + mi * 16 + lane15) * 32 + sw];
#pragma unroll
            for (int ni = 0; ni < 4; ++ni)
                bfr[ni] = *(const bf16x8*)&Bs[cur][(wn + ni * 16 + lane15) * 32 + sw];
#pragma unroll
            for (int mi = 0; mi < 4; ++mi)
#pragma unroll
                for (int ni = 0; ni < 4; ++ni)
                    acc[mi][ni] = __builtin_amdgcn_mfma_f32_16x16x32_bf16(
                        af[mi], bfr[ni], acc[mi][ni], 0, 0, 0);
        } else {
#pragma unroll
            for (int ks = 0; ks < 2; ++ks) {
                int sw = (((ks * 4 + quad) ^ (lane15 & 7)) * 8);
                bf16x8 af[4], bfr[4];
#pragma unroll
                for (int mi = 0; mi < 4; ++mi)
                    af[mi] = *(const bf16x8*)&As[cur][(wm + mi * 16 + lane15) * 64 + sw];
#pragma unroll
                for (int ni = 0; ni < 4; ++ni)
                    bfr[ni] = *(const bf16x8*)&Bs[cur][(wn + ni * 16 + lane15) * 64 + sw];
#pragma unroll
                for (int mi = 0; mi < 4; ++mi)
#pragma unroll
                    for (int ni = 0; ni < 4; ++ni)
                        acc[mi][ni] = __builtin_amdgcn_mfma_f32_16x16x32_bf16(
                            af[mi], bfr[ni], acc[mi][ni], 0, 0, 0);
            }
        }
        __syncthreads();   // drains vmcnt: tile t+1 resident; reads of cur done
        cur ^= 1;
    }

#pragma unroll
    for (int mi = 0; mi < 4; ++mi) {
#pragma unroll
        for (int r = 0; r < 4; ++r) {
            int gm = bm0 + wm + mi * 16 + quad * 4 + r;
#pragma unroll
            for (int ni = 0; ni < 4; ++ni) {
                int gn = bn0 + wn + ni * 16 + lane15;
                float v = acc[mi][ni][r];
                if (HAS_BIAS) v += bias[gn];
                if (HAS_RES)  v += ldf(res + (size_t)gm * ldr + gn);
                if (RELU)     v = fmaxf(v, 0.f);
                stf(Cm + (size_t)gm * ldc + gn, v);
            }
        }
    }
}

// ---------------------------------------------------------------------------
// One q-tile's work for one 64-key tile: QK^T (S^T form), online softmax in
// exp2 domain, P->LDS (wave-private), PV. All state per-lane/per-wave.
// ---------------------------------------------------------------------------
__device__ __forceinline__ void attn_tile_q(
    const short* __restrict__ Ks, const short* __restrict__ Vs,
    short* __restrict__ Psw,
    const bf16x8* qf, f32x4* oacc, float& mrun, float& lrun,
    int ktbase, int qmin, int quad, int lane15, int r7)
{
    const float scale2 = 0.18033688011112042f;   // (1/8) * log2(e)
    const int PS = 72;
    f32x4 sacc[4] = {};
    __builtin_amdgcn_s_setprio(1);
#pragma unroll
    for (int ks = 0; ks < 2; ++ks) {
        int so = ((ks * 4 + quad) ^ r7) * 8;
#pragma unroll
        for (int mi = 0; mi < 4; ++mi) {
            bf16x8 kf = *(const bf16x8*)&Ks[(mi * 16 + lane15) * 64 + so];
            sacc[mi] = __builtin_amdgcn_mfma_f32_16x16x32_bf16(kf, qf[ks], sacc[mi], 0, 0, 0);
        }
    }
    __builtin_amdgcn_s_setprio(0);

    // causal mask (only diagonal-crossing tiles)
    if (ktbase + 63 > qmin) {
        int ql = qmin + lane15;
#pragma unroll
        for (int mi = 0; mi < 4; ++mi)
#pragma unroll
            for (int r = 0; r < 4; ++r)
                if (ktbase + mi * 16 + quad * 4 + r > ql) sacc[mi][r] = -3e38f;
    }

    // row max (16 keys in-lane, cross-quad reduce)
    float mx = sacc[0][0];
#pragma unroll
    for (int mi = 0; mi < 4; ++mi)
#pragma unroll
        for (int r = 0; r < 4; ++r) mx = fmaxf(mx, sacc[mi][r]);
    mx = fmaxf(mx, __shfl_xor(mx, 16, 64));
    mx = fmaxf(mx, __shfl_xor(mx, 32, 64));
    float pmax = mx * scale2;

    // T13 defer-max (threshold 11.5 log2-units ~= e^8)
    if (!__all(pmax <= mrun + 11.5f)) {
        float mn = fmaxf(mrun, pmax);
        float alpha = exp2f(mrun - mn);
        mrun = mn;
        lrun *= alpha;
#pragma unroll
        for (int di = 0; di < 4; ++di)
#pragma unroll
            for (int r = 0; r < 4; ++r) oacc[di][r] *= alpha;
    }

    float psum = 0.f;
#pragma unroll
    for (int mi = 0; mi < 4; ++mi) {
        float p[4];
#pragma unroll
        for (int r = 0; r < 4; ++r) {
            p[r] = exp2f(fmaf(sacc[mi][r], scale2, -mrun));
            psum += p[r];
        }
        short tmp[4];
#pragma unroll
        for (int r = 0; r < 4; ++r) {
            bf16 pb = f2b(p[r]);
            tmp[r] = *(short*)&pb;
        }
        *(s16x4*)&Psw[lane15 * PS + mi * 16 + quad * 4] = *(s16x4*)tmp;
    }
    lrun += psum;

    // O^T += V^T P^T  (wave-private Psw: no barrier needed)
    __builtin_amdgcn_s_setprio(1);
#pragma unroll
    for (int ks = 0; ks < 2; ++ks) {
        int so = ((ks * 4 + quad) ^ r7) * 8;
        bf16x8 pf = *(const bf16x8*)&Psw[lane15 * PS + ks * 32 + quad * 8];
#pragma unroll
        for (int di = 0; di < 4; ++di) {
            bf16x8 vf = *(const bf16x8*)&Vs[(di * 16 + lane15) * 64 + so];
            oacc[di] = __builtin_amdgcn_mfma_f32_16x16x32_bf16(vf, pf, oacc[di], 0, 0, 0);
        }
    }
    __builtin_amdgcn_s_setprio(0);
}

// ---------------------------------------------------------------------------
// MFMA causal flash attention, S^T form, 512 thr = 8 waves.
// CAUSAL-BALANCED DUAL Q-TILE: block bx processes q-tiles (15-bx, bx) in ONE
// k-loop sharing K/V staging. Every block does exactly 34 tile-units ->
// uniform duration, 512 blocks = 2/CU all co-resident, no dispatch tail.
// ---------------------------------------------------------------------------
__global__ __launch_bounds__(512, 4) void attn_kernel(
    const bf16* __restrict__ qkv, const bf16* __restrict__ vt,
    bf16* __restrict__ o, int T)
{
    const int LDQ = 3072;
    const int PS = 72;   // Ps row stride (shorts): 144 B, 16B-aligned
    int bx = blockIdx.x;
    int qta = 15 - bx;                 // heavy tile (processed first)
    int qtb = bx;                      // light tile (shares K/V range prefix)
    int h = blockIdx.y, b = blockIdx.z;
    int tid = threadIdx.x, wv = tid >> 6, ln = tid & 63;
    int quad = ln >> 4, lane15 = ln & 15, r7 = lane15 & 7;

    __shared__ short KV[2][2][64 * 64];   // [buf][0=K [key][d], 1=V [d][key]]
    __shared__ short Ps[2][8][16 * PS];   // [qtile][wave][qrow16][key64]

    int lr = ln >> 3;                     // 0..7: row within 8-row chunk
    int lc = ((ln & 7) ^ lr) * 8;         // swizzled source col offset

    const bf16* kbase = qkv + (size_t)(b * T) * LDQ + 1024 + h * 64;
    const bf16* vbase = vt + (size_t)((b * 16 + h) * 64) * T;

    // ---- stage BOTH Q tiles (each 128x64) into the KV area, read to regs
#pragma unroll
    for (int i = 0; i < 2; ++i) {
        int ch = wv * 2 + i;
        load_lds16(qkv + (size_t)(b * T + qta * 128 + ch * 8 + lr) * LDQ + h * 64 + lc,
                   &KV[0][0][ch * 512]);
        load_lds16(qkv + (size_t)(b * T + qtb * 128 + ch * 8 + lr) * LDQ + h * 64 + lc,
                   &KV[1][0][ch * 512]);
    }
    __syncthreads();   // Q staged (vmcnt drained by barrier)
    bf16x8 qfa[2], qfb[2];
#pragma unroll
    for (int ks = 0; ks < 2; ++ks) {
        int off = (wv * 16 + lane15) * 64 + (((ks * 4 + quad) ^ r7) * 8);
        qfa[ks] = *(const bf16x8*)&KV[0][0][off];
        qfb[ks] = *(const bf16x8*)&KV[1][0][off];
    }
    __syncthreads();   // all Q reads done before K/V overwrite

    f32x4 oacca[4] = {}, oaccb[4] = {};
    float mra = -1e30f, lra = 0.f, mrb = -1e30f, lrb = 0.f;
    int qmina = qta * 128 + wv * 16;
    int qminb = qtb * 128 + wv * 16;
    int ntiles = 2 * qta + 2;

    // prefetch tile 0 into buf 0 (wave wv stages rows wv*8..wv*8+7)
    load_lds16(kbase + (size_t)(wv * 8 + lr) * LDQ + lc, &KV[0][0][wv * 8 * 64]);
    load_lds16(vbase + (size_t)(wv * 8 + lr) * T + lc, &KV[0][1][wv * 8 * 64]);

    for (int kt = 0; kt < ntiles; ++kt) {
        __syncthreads();   // tile kt published (barrier drains vmcnt)
        if (kt + 1 < ntiles) {
            int nb = (kt + 1) & 1;
            load_lds16(kbase + (size_t)((kt + 1) * 64 + wv * 8 + lr) * LDQ + lc,
                       &KV[nb][0][wv * 8 * 64]);
            load_lds16(vbase + (size_t)(wv * 8 + lr) * T + (kt + 1) * 64 + lc,
                       &KV[nb][1][wv * 8 * 64]);
        }
        const short* Ks = &KV[kt & 1][0][0];
        const short* Vs = &KV[kt & 1][1][0];
        int kb = kt * 64;

        if (kb <= qmina + 15)
            attn_tile_q(Ks, Vs, &Ps[0][wv][0], qfa, oacca, mra, lra,
                        kb, qmina, quad, lane15, r7);
        if (kb <= qminb + 15)
            attn_tile_q(Ks, Vs, &Ps[1][wv][0], qfb, oaccb, mrb, lrb,
                        kb, qminb, quad, lane15, r7);
    }

    // ---- epilogue: cross-quad l reduce + store, both q-tiles
    lra += __shfl_xor(lra, 16, 64);
    lra += __shfl_xor(lra, 32, 64);
    float inva = 1.f / lra;
    size_t rowa = (size_t)(b * T + qta * 128 + wv * 16 + lane15);
#pragma unroll
    for (int di = 0; di < 4; ++di) {
        short tmp[4];
#pragma unroll
        for (int r = 0; r < 4; ++r) {
            bf16 ob = f2b(oacca[di][r] * inva);
            tmp[r] = *(short*)&ob;
        }
        *(s16x4*)&o[rowa * 1024 + h * 64 + di * 16 + quad * 4] = *(s16x4*)tmp;
    }

    lrb += __shfl_xor(lrb, 16, 64);
    lrb += __shfl_xor(lrb, 32, 64);
    float invb = 1.f / lrb;
    size_t rowb = (size_t)(b * T + qtb * 128 + wv * 16 + lane15);
#pragma unroll
    for (int di = 0; di < 4; ++di) {
        short tmp[4];
#pragma unroll
        for (int r = 0; r < 4; ++r) {
            bf16 ob = f2b(oaccb[di][r] * invb);
            tmp[r] = *(short*)&ob;
        }
        *(s16x4*)&o[rowb * 1024 + h * 64 + di * 16 + quad * 4] = *(s16x4*)tmp;
    }
}

// ---------------------------------------------------------------------------
extern "C" void kernel_launch(void* const* d_in, const int* in_sizes, int n_in,
                              void* d_out, int out_size, void* d_ws, size_t ws_size,
                              hipStream_t stream)
{
    (void)in_sizes; (void)n_in; (void)out_size; (void)ws_size;
    const float* x   = (const float*)d_in[0];
    const float* Wq  = (const float*)d_in[1];
    const float* Wk  = (const float*)d_in[2];
    const float* Wv  = (const float*)d_in[3];
    const float* Wo  = (const float*)d_in[4];
    const float* bo  = (const float*)d_in[5];
    const float* g1  = (const float*)d_in[6];
    const float* be1 = (const float*)d_in[7];
    const float* g2  = (const float*)d_in[8];
    const float* be2 = (const float*)d_in[9];
    const float* W1  = (const float*)d_in[10];
    const float* b1  = (const float*)d_in[11];
    const float* W2  = (const float*)d_in[12];
    const float* b2  = (const float*)d_in[13];

    const int T = 2048, M = 4 * T;  // 8192 rows
    const size_t MB = 1ull << 20;
    char* ws = (char*)d_ws;

    // workspace map (128 MB, live-range overlays):
    bf16*  xn    = (bf16*)(ws + 0 * MB);     // 16 MB; later: attnb; later: hb
    bf16*  qkv   = (bf16*)(ws + 16 * MB);    // 48 MB [M][3072]; later: hb tail
    bf16*  vt    = (bf16*)(ws + 64 * MB);    // 16 MB [b*16+h][64][T]
    bf16*  wqkvt = (bf16*)(ws + 80 * MB);    //  6 MB [3072][1024]; later: x1b
    bf16*  x1b   = (bf16*)(ws + 80 * MB);    // 16 MB [M][1024] bf16 residual
    bf16*  wot   = (bf16*)(ws + 96 * MB);    //  2 MB; later: xn2
    bf16*  xn2   = (bf16*)(ws + 96 * MB);    // 16 MB
    bf16*  w1t   = (bf16*)(ws + 112 * MB);   //  8 MB [4096][1024]
    bf16*  w2t   = (bf16*)(ws + 120 * MB);   //  8 MB [1024][4096]
    bf16*  attnb = (bf16*)(ws + 0 * MB);
    bf16*  hb    = (bf16*)(ws + 0 * MB);     // 64 MB [M][4096]

    dim3 blk(256);

    prep_weights<<<12288, blk, 0, stream>>>(Wq, Wk, Wv, Wo, W1, W2,
                                            wqkvt, wot, w1t, w2t);

    ln_kernel<float><<<M, blk, 0, stream>>>(x, g1, be1, xn);

    gemm_bt<32, false, false, false, float, bf16><<<dim3(24, 64), blk, 0, stream>>>(
        xn, 1024, wqkvt, 1024, nullptr, nullptr, 0, qkv, 3072, M, 3072, 1024);

    vt_kernel<<<dim3(2, T / 32, 64), blk, 0, stream>>>(qkv, vt, T);

    attn_kernel<<<dim3(8, 16, 4), dim3(512), 0, stream>>>(qkv, vt, attnb, T);

    gemm_bt<32, false, true, true, float, bf16><<<dim3(8, 64), blk, 0, stream>>>(
        attnb, 1024, wot, 1024, bo, x, 1024, x1b, 1024, M, 1024, 1024);

    ln_kernel<bf16><<<M, blk, 0, stream>>>(x1b, g2, be2, xn2);

    gemm_bt<32, true, true, false, float, bf16><<<dim3(32, 64), blk, 0, stream>>>(
        xn2, 1024, w1t, 1024, b1, nullptr, 0, hb, 4096, M, 4096, 1024);

    gemm_bt<64, false, true, true, bf16, float><<<dim3(8, 64), blk, 0, stream>>>(
        hb, 4096, w2t, 4096, b2, x1b, 1024, (float*)d_out, 1024, M, 1024, 4096);
}